// Round 1
// baseline (1207.676 us; speedup 1.0000x reference)
//
#include <hip/hip_runtime.h>
#include <math.h>

#define HID 2048
#define NB 32
#define NH 16
#define HD 128
#define SMAX 2048

// ---------------------------------------------------------------- init ------
__global__ __launch_bounds__(256) void init_bias_kernel(
    const float* __restrict__ bq, const float* __restrict__ bk,
    const float* __restrict__ bv, const float* __restrict__ bo,
    float* __restrict__ qkv, float* __restrict__ out) {
  int i = blockIdx.x * 256 + threadIdx.x;   // 0..65535 (= 32*2048)
  int n = i & (HID - 1);
  qkv[i]          = bq[n];
  qkv[i + 65536]  = bk[n];
  qkv[i + 131072] = bv[n];
  out[i]          = bo[n];
}

// ------------------------------------------------------------- qkv gemm -----
// blockIdx: [mat(3)][nchunk(8)][kchunk(16)] = 384 blocks, 256 threads.
// Each thread owns one output column n for all 32 rows, over a 128-wide k slice.
__global__ __launch_bounds__(256) void qkv_gemm_kernel(
    const float* __restrict__ x,
    const float* __restrict__ Wq, const float* __restrict__ Wk,
    const float* __restrict__ Wv, float* __restrict__ qkv) {
  int blk = blockIdx.x;
  int kchunk = blk & 15;
  int nchunk = (blk >> 4) & 7;
  int mat = blk >> 7;
  const float* W = (mat == 0) ? Wq : (mat == 1) ? Wk : Wv;
  int n = nchunk * 256 + threadIdx.x;
  int k0 = kchunk * 128;
  float acc[NB];
#pragma unroll
  for (int m = 0; m < NB; ++m) acc[m] = 0.f;
  const float* Wp = W + (size_t)k0 * HID + n;
  for (int kk = 0; kk < 128; kk += 8) {
    float w8[8];
#pragma unroll
    for (int u = 0; u < 8; ++u) w8[u] = Wp[(size_t)(kk + u) * HID];
#pragma unroll
    for (int m = 0; m < NB; ++m) {
      const float* xp = x + m * HID + k0 + kk;   // wave-uniform -> s_load
      float a = acc[m];
#pragma unroll
      for (int u = 0; u < 8; ++u) a = fmaf(xp[u], w8[u], a);
      acc[m] = a;
    }
  }
  float* op = qkv + mat * 65536 + n;
#pragma unroll
  for (int m = 0; m < NB; ++m) atomicAdd(op + m * HID, acc[m]);
}

// ------------------------------------------------------------ attention -----
// One block per (b,h): 512 blocks x 512 threads (8 waves).
// Wave lane layout: lanes 0-31 = position sA, lanes 32-63 = sA+... (half),
// each lane holds a float4 of the 128-d head row.
__global__ __launch_bounds__(512) void attn_kernel(
    const float* __restrict__ qkv,
    const float* __restrict__ kcache, const float* __restrict__ vcache,
    const int* __restrict__ block_table, const int* __restrict__ seq_lens,
    float* __restrict__ attn_out) {
  int b = blockIdx.x >> 4;
  int h = blockIdx.x & 15;
  int tid = threadIdx.x;
  int wave = tid >> 6;
  int lane = tid & 63;
  int half = (lane >> 5) & 1;
  int l32 = lane & 31;

  __shared__ float sc[SMAX];
  __shared__ float red[16];
  __shared__ float opart[8][HD];

  int S = seq_lens[b];
  int plast = S - 1;
  const int* bt = block_table + b * 128;
  const float* qp   = qkv + b * HID + h * HD;
  const float* kovr = qkv + 65536  + b * HID + h * HD;  // fresh k (cache not written)
  const float* vovr = qkv + 131072 + b * HID + h * HD;  // fresh v

  float4 qv = *(const float4*)(qp + l32 * 4);
  const float scale = 0.08838834764831845f;  // 128^-0.5

  // ---- pass 1: scores -> LDS
  for (int s0 = wave * 4 + half; s0 < S; s0 += 32) {
    int sA = s0;
    int sB = s0 + 2;
    bool vB = sB < S;
    int sBc = vB ? sB : sA;
    const float* pA = (sA == plast) ? kovr
        : kcache + (size_t)(bt[sA >> 4] * 16 + (sA & 15)) * 2048 + h * HD;
    const float* pB = (sBc == plast) ? kovr
        : kcache + (size_t)(bt[sBc >> 4] * 16 + (sBc & 15)) * 2048 + h * HD;
    float4 ka = *(const float4*)(pA + l32 * 4);
    float4 kb = *(const float4*)(pB + l32 * 4);
    float dA = ka.x * qv.x + ka.y * qv.y + ka.z * qv.z + ka.w * qv.w;
    float dB = kb.x * qv.x + kb.y * qv.y + kb.z * qv.z + kb.w * qv.w;
#pragma unroll
    for (int m = 1; m <= 16; m <<= 1) {
      dA += __shfl_xor(dA, m, 64);
      dB += __shfl_xor(dB, m, 64);
    }
    if (l32 == 0) {
      sc[sA] = dA * scale;
      if (vB) sc[sB] = dB * scale;
    }
  }
  __syncthreads();

  // ---- block max
  float mx = -1e30f;
  for (int s = tid; s < S; s += 512) mx = fmaxf(mx, sc[s]);
#pragma unroll
  for (int m = 1; m <= 32; m <<= 1) mx = fmaxf(mx, __shfl_xor(mx, m, 64));
  if (lane == 0) red[wave] = mx;
  __syncthreads();
  float M = red[0];
#pragma unroll
  for (int w = 1; w < 8; ++w) M = fmaxf(M, red[w]);

  // ---- exp + sum (rewrite sc in place)
  float lsum = 0.f;
  for (int s = tid; s < S; s += 512) {
    float p = __expf(sc[s] - M);
    sc[s] = p;
    lsum += p;
  }
#pragma unroll
  for (int m = 1; m <= 32; m <<= 1) lsum += __shfl_xor(lsum, m, 64);
  if (lane == 0) red[8 + wave] = lsum;
  __syncthreads();
  float SUM = 0.f;
#pragma unroll
  for (int w = 0; w < 8; ++w) SUM += red[8 + w];
  float rsum = 1.0f / SUM;

  // ---- pass 2: probs . V
  float4 acc = make_float4(0.f, 0.f, 0.f, 0.f);
  for (int s0 = wave * 4 + half; s0 < S; s0 += 32) {
    int sA = s0;
    int sB = s0 + 2;
    bool vB = sB < S;
    int sBc = vB ? sB : sA;
    const float* pA = (sA == plast) ? vovr
        : vcache + (size_t)(bt[sA >> 4] * 16 + (sA & 15)) * 2048 + h * HD;
    const float* pB = (sBc == plast) ? vovr
        : vcache + (size_t)(bt[sBc >> 4] * 16 + (sBc & 15)) * 2048 + h * HD;
    float4 va = *(const float4*)(pA + l32 * 4);
    float4 vb = *(const float4*)(pB + l32 * 4);
    float pa = sc[sA];
    float pb = vB ? sc[sBc] : 0.f;
    acc.x = fmaf(pa, va.x, acc.x); acc.y = fmaf(pa, va.y, acc.y);
    acc.z = fmaf(pa, va.z, acc.z); acc.w = fmaf(pa, va.w, acc.w);
    acc.x = fmaf(pb, vb.x, acc.x); acc.y = fmaf(pb, vb.y, acc.y);
    acc.z = fmaf(pb, vb.z, acc.z); acc.w = fmaf(pb, vb.w, acc.w);
  }
  acc.x += __shfl_down(acc.x, 32, 64);
  acc.y += __shfl_down(acc.y, 32, 64);
  acc.z += __shfl_down(acc.z, 32, 64);
  acc.w += __shfl_down(acc.w, 32, 64);
  if (half == 0) *(float4*)(&opart[wave][l32 * 4]) = acc;
  __syncthreads();
  if (tid < HD) {
    float o = 0.f;
#pragma unroll
    for (int w = 0; w < 8; ++w) o += opart[w][tid];
    attn_out[b * HID + h * HD + tid] = o * rsum;
  }
}

// ------------------------------------------------------------- out gemm -----
__global__ __launch_bounds__(256) void out_gemm_kernel(
    const float* __restrict__ X, const float* __restrict__ Wo,
    float* __restrict__ out) {
  int blk = blockIdx.x;        // 128 blocks: [nchunk(8)][kchunk(16)]
  int kchunk = blk & 15;
  int nchunk = blk >> 4;
  int n = nchunk * 256 + threadIdx.x;
  int k0 = kchunk * 128;
  float acc[NB];
#pragma unroll
  for (int m = 0; m < NB; ++m) acc[m] = 0.f;
  const float* Wp = Wo + (size_t)k0 * HID + n;
  for (int kk = 0; kk < 128; kk += 8) {
    float w8[8];
#pragma unroll
    for (int u = 0; u < 8; ++u) w8[u] = Wp[(size_t)(kk + u) * HID];
#pragma unroll
    for (int m = 0; m < NB; ++m) {
      const float* xp = X + m * HID + k0 + kk;
      float a = acc[m];
#pragma unroll
      for (int u = 0; u < 8; ++u) a = fmaf(xp[u], w8[u], a);
      acc[m] = a;
    }
  }
#pragma unroll
  for (int m = 0; m < NB; ++m) atomicAdd(out + m * HID + n, acc[m]);
}

// ---------------------------------------------------------------------------
extern "C" void kernel_launch(void* const* d_in, const int* in_sizes, int n_in,
                              void* d_out, int out_size, void* d_ws, size_t ws_size,
                              hipStream_t stream) {
  (void)in_sizes; (void)n_in; (void)out_size; (void)ws_size;
  const float* x      = (const float*)d_in[0];
  const float* Wq     = (const float*)d_in[1];
  const float* bq     = (const float*)d_in[2];
  const float* Wk     = (const float*)d_in[3];
  const float* bk     = (const float*)d_in[4];
  const float* Wv     = (const float*)d_in[5];
  const float* bv     = (const float*)d_in[6];
  const float* Wo     = (const float*)d_in[7];
  const float* bo     = (const float*)d_in[8];
  const float* kcache = (const float*)d_in[9];
  const float* vcache = (const float*)d_in[10];
  const int* block_table = (const int*)d_in[13];
  const int* seq_lens    = (const int*)d_in[14];
  float* out = (float*)d_out;
  float* qkv = (float*)d_ws;             // [3][32][2048] fp32
  float* attn_out = qkv + 3 * 65536;     // [32][2048] fp32

  hipLaunchKernelGGL(init_bias_kernel, dim3(256), dim3(256), 0, stream,
                     bq, bk, bv, bo, qkv, out);
  hipLaunchKernelGGL(qkv_gemm_kernel, dim3(384), dim3(256), 0, stream,
                     x, Wq, Wk, Wv, qkv);
  hipLaunchKernelGGL(attn_kernel, dim3(512), dim3(512), 0, stream,
                     qkv, kcache, vcache, block_table, seq_lens, attn_out);
  hipLaunchKernelGGL(out_gemm_kernel, dim3(128), dim3(256), 0, stream,
                     attn_out, Wo, out);
}